// Round 1
// baseline (1401.402 us; speedup 1.0000x reference)
//
#include <hip/hip_runtime.h>

static constexpr int D = 128;

// ---------------------------------------------------------------------------
// Phase 1: scatter-add  agg[dst] += x[src]  for every edge.
// 32 lanes per edge; each lane moves one float4 (16B) => 512B per edge.
// x is never written (inputs must not be mutated); agg lives in d_ws.
// ---------------------------------------------------------------------------
__global__ __launch_bounds__(256) void gnn_scatter(
    const float* __restrict__ x, const int* __restrict__ ei,
    float* __restrict__ agg, int E) {
  long t = (long)blockIdx.x * blockDim.x + threadIdx.x;
  long e = t >> 5;  // 32 lanes per edge
  if (e >= E) return;
  int lane = (int)(t & 31);
  int s = ei[e];            // src
  int d = ei[(long)E + e];  // dst
  const float4 v =
      reinterpret_cast<const float4*>(x)[(long)s * (D / 4) + lane];
  float* o = agg + (long)d * D + lane * 4;
  atomicAdd(o + 0, v.x);
  atomicAdd(o + 1, v.y);
  atomicAdd(o + 2, v.z);
  atomicAdd(o + 3, v.w);
}

// ---------------------------------------------------------------------------
// Phase 2: out[i][o] = sum_k (agg[i][k] + x[i][k]) * W[o][k]
// W (128x128, [out][in] row-major) transposed into LDS as Wt[k][o].
// Block: 256 threads, 128 rows. Thread = (rowgroup rg: 4 rows, colgroup cg:
// 16 cols). LDS float4 reads rotated by rg so a wave's 64 lanes cover all 32
// bank-quads of a W row. acc indices are compile-time (runtime only in the
// LDS/store ADDRESS) to avoid scratch spills.
// ---------------------------------------------------------------------------
__global__ __launch_bounds__(256) void gnn_gemm(
    const float* __restrict__ agg, const float* __restrict__ x,
    const float* __restrict__ W, float* __restrict__ out, int N) {
  __shared__ float Wt[D * D];  // 64 KB: Wt[k*128 + o]
  const int tid = threadIdx.x;

  // Cooperative transpose W[o][k] -> Wt[k][o]. Coalesced global reads;
  // the column-wise LDS writes bank-conflict but this is one-time (~64 waves
  // of writes per block) vs the 128-deep K loop below.
  for (int idx = tid; idx < D * D; idx += 256) {
    int o = idx >> 7, k = idx & 127;
    Wt[k * D + o] = W[idx];
  }
  __syncthreads();

  const int cg = tid & 7;   // columns cg*16 .. cg*16+15
  const int rg = tid >> 3;  // rows row0 .. row0+3
  const long row0 = (long)blockIdx.x * 128 + (long)rg * 4;

  float4 acc[4][4];  // acc[r][jj] holds column quad ((jj+rg)&3) of this thread
#pragma unroll
  for (int r = 0; r < 4; ++r)
#pragma unroll
    for (int j = 0; j < 4; ++j) acc[r][j] = make_float4(0.f, 0.f, 0.f, 0.f);

  long rofs[4];
  bool val[4];
#pragma unroll
  for (int r = 0; r < 4; ++r) {
    long rr = row0 + r;
    val[r] = rr < N;
    rofs[r] = (val[r] ? rr : (long)(N - 1)) * (D / 4);  // clamp: safe loads
  }

  const float4* agg4 = reinterpret_cast<const float4*>(agg);
  const float4* x4 = reinterpret_cast<const float4*>(x);

  for (int k4 = 0; k4 < D / 4; ++k4) {
    float a[4][4];
#pragma unroll
    for (int r = 0; r < 4; ++r) {
      float4 av = agg4[rofs[r] + k4];
      float4 xv = x4[rofs[r] + k4];
      a[r][0] = av.x + xv.x;
      a[r][1] = av.y + xv.y;
      a[r][2] = av.z + xv.z;
      a[r][3] = av.w + xv.w;
    }
#pragma unroll
    for (int kk = 0; kk < 4; ++kk) {
      const int k = k4 * 4 + kk;
      const float* wrow = &Wt[k * D + cg * 16];
#pragma unroll
      for (int jj = 0; jj < 4; ++jj) {
        const float4 wv =
            *reinterpret_cast<const float4*>(wrow + (((jj + rg) & 3) << 2));
#pragma unroll
        for (int r = 0; r < 4; ++r) {
          acc[r][jj].x += a[r][kk] * wv.x;
          acc[r][jj].y += a[r][kk] * wv.y;
          acc[r][jj].z += a[r][kk] * wv.z;
          acc[r][jj].w += a[r][kk] * wv.w;
        }
      }
    }
  }

#pragma unroll
  for (int r = 0; r < 4; ++r) {
    if (!val[r]) continue;
    float* orow = out + (row0 + r) * D + cg * 16;
#pragma unroll
    for (int jj = 0; jj < 4; ++jj) {
      *reinterpret_cast<float4*>(orow + (((jj + rg) & 3) << 2)) = acc[r][jj];
    }
  }
}

extern "C" void kernel_launch(void* const* d_in, const int* in_sizes, int n_in,
                              void* d_out, int out_size, void* d_ws,
                              size_t ws_size, hipStream_t stream) {
  const float* x = (const float*)d_in[0];
  const int* ei = (const int*)d_in[1];  // [2, E]: first E = src, next E = dst
  const float* W = (const float*)d_in[2];
  float* out = (float*)d_out;

  const int N = in_sizes[0] / D;
  const int E = in_sizes[1] / 2;

  float* agg = (float*)d_ws;  // N*D floats = 25.6 MB scratch

  // agg must be zeroed EVERY call (harness does not re-poison between replays).
  hipMemsetAsync(agg, 0, (size_t)N * D * sizeof(float), stream);

  {
    long threads = (long)E * 32;
    int blocks = (int)((threads + 255) / 256);
    gnn_scatter<<<blocks, 256, 0, stream>>>(x, ei, agg, E);
  }
  {
    int blocks = (N + 127) / 128;
    gnn_gemm<<<blocks, 256, 0, stream>>>(agg, x, W, out, N);
  }
}

// Round 2
// 312.222 us; speedup vs baseline: 4.4885x; 4.4885x over previous
//
#include <hip/hip_runtime.h>

static constexpr int D = 128;

// ---------------------------------------------------------------------------
// CSR build, phase A: histogram of dst. counts must be pre-zeroed.
// ---------------------------------------------------------------------------
__global__ __launch_bounds__(256) void gnn_hist(const int* __restrict__ ei,
                                                int* __restrict__ counts,
                                                int E) {
  int e = blockIdx.x * 256 + threadIdx.x;
  if (e < E) atomicAdd(&counts[ei[E + e]], 1);
}

// ---------------------------------------------------------------------------
// CSR build, phase B: single-block exclusive scan of counts -> offs (N+1),
// and a second copy into cursor (consumed by the fill kernel's atomics).
// ---------------------------------------------------------------------------
__global__ __launch_bounds__(1024) void gnn_scan(const int* __restrict__ counts,
                                                 int* __restrict__ offs,
                                                 int* __restrict__ cursor,
                                                 int N) {
  __shared__ int sc[1024];
  const int tid = threadIdx.x;
  const int chunk = (N + 1023) >> 10;
  const int begin = tid * chunk;
  const int end = min(begin + chunk, N);
  int s = 0;
  for (int i = begin; i < end; ++i) s += counts[i];
  sc[tid] = s;
  __syncthreads();
  // Hillis-Steele inclusive scan over the 1024 per-thread sums.
  for (int off = 1; off < 1024; off <<= 1) {
    int v = (tid >= off) ? sc[tid - off] : 0;
    __syncthreads();
    sc[tid] += v;
    __syncthreads();
  }
  int run = (tid > 0) ? sc[tid - 1] : 0;  // exclusive prefix of this chunk
  for (int i = begin; i < end; ++i) {
    offs[i] = run;
    cursor[i] = run;
    run += counts[i];
  }
  if (end == N) offs[N] = run;  // all qualifying threads write the same total
}

// ---------------------------------------------------------------------------
// CSR build, phase C: scatter each edge's src into its dst segment.
// ---------------------------------------------------------------------------
__global__ __launch_bounds__(256) void gnn_fill(const int* __restrict__ ei,
                                                int* __restrict__ cursor,
                                                int* __restrict__ esrc,
                                                int E) {
  int e = blockIdx.x * 256 + threadIdx.x;
  if (e >= E) return;
  int s = ei[e];
  int d = ei[E + e];
  int slot = atomicAdd(&cursor[d], 1);
  esrc[slot] = s;
}

// ---------------------------------------------------------------------------
// Gather: aggs[j] = x[j] + sum_{e in seg(j)} x[esrc[e]].
// 32 lanes per node, one float4 per lane (512 B coalesced row reads; x is
// fully L3-resident). aggs == d_out (consumed in-place by the GEMM).
// ---------------------------------------------------------------------------
__global__ __launch_bounds__(256) void gnn_gather(const float* __restrict__ x,
                                                  const int* __restrict__ offs,
                                                  const int* __restrict__ esrc,
                                                  float* __restrict__ aggs,
                                                  int N) {
  int j = blockIdx.x * 8 + (threadIdx.x >> 5);
  if (j >= N) return;
  int c = threadIdx.x & 31;
  const float4* x4 = reinterpret_cast<const float4*>(x);
  float4 acc = x4[j * 32 + c];  // self loop
  const int b = offs[j], en = offs[j + 1];
  for (int e = b; e < en; ++e) {
    int s = esrc[e];
    float4 v = x4[s * 32 + c];
    acc.x += v.x;
    acc.y += v.y;
    acc.z += v.z;
    acc.w += v.w;
  }
  reinterpret_cast<float4*>(aggs)[j * 32 + c] = acc;
}

// ---------------------------------------------------------------------------
// GEMM, IN PLACE on hx (= d_out): hx[i][o] <- sum_k hx[i][k] * W[o][k].
// Each block owns rows [blockIdx*128, +128) — it reads only those rows and
// (after a barrier) overwrites only those rows, so in-place is safe.
// W transposed into LDS as Wt[k][o]; LDS float4 reads rotated by rowgroup to
// spread bank quads. acc indices compile-time (no scratch spill).
// ---------------------------------------------------------------------------
__global__ __launch_bounds__(256) void gnn_gemm(const float* __restrict__ W,
                                                float* hx, int N) {
  __shared__ float Wt[D * D];  // 64 KB: Wt[k*128 + o]
  const int tid = threadIdx.x;

  for (int idx = tid; idx < D * D; idx += 256) {
    int o = idx >> 7, k = idx & 127;
    Wt[k * D + o] = W[idx];
  }
  __syncthreads();

  const int cg = tid & 7;   // columns cg*16 .. cg*16+15
  const int rg = tid >> 3;  // rows row0 .. row0+3
  const long row0 = (long)blockIdx.x * 128 + (long)rg * 4;

  float4 acc[4][4];
#pragma unroll
  for (int r = 0; r < 4; ++r)
#pragma unroll
    for (int j = 0; j < 4; ++j) acc[r][j] = make_float4(0.f, 0.f, 0.f, 0.f);

  long rofs[4];
  bool val[4];
#pragma unroll
  for (int r = 0; r < 4; ++r) {
    long rr = row0 + r;
    val[r] = rr < N;
    // clamp to a row inside THIS block's range (last block owns row N-1)
    rofs[r] = (val[r] ? rr : (long)(N - 1)) * (D / 4);
  }

  const float4* hx4 = reinterpret_cast<const float4*>(hx);

  for (int k4 = 0; k4 < D / 4; ++k4) {
    float a[4][4];
#pragma unroll
    for (int r = 0; r < 4; ++r) {
      float4 av = hx4[rofs[r] + k4];
      a[r][0] = av.x;
      a[r][1] = av.y;
      a[r][2] = av.z;
      a[r][3] = av.w;
    }
#pragma unroll
    for (int kk = 0; kk < 4; ++kk) {
      const int k = k4 * 4 + kk;
      const float* wrow = &Wt[k * D + cg * 16];
#pragma unroll
      for (int jj = 0; jj < 4; ++jj) {
        const float4 wv =
            *reinterpret_cast<const float4*>(wrow + (((jj + rg) & 3) << 2));
#pragma unroll
        for (int r = 0; r < 4; ++r) {
          acc[r][jj].x += a[r][kk] * wv.x;
          acc[r][jj].y += a[r][kk] * wv.y;
          acc[r][jj].z += a[r][kk] * wv.z;
          acc[r][jj].w += a[r][kk] * wv.w;
        }
      }
    }
  }

  __syncthreads();  // all reads of this block's rows complete before stores

#pragma unroll
  for (int r = 0; r < 4; ++r) {
    if (!val[r]) continue;
    float* orow = hx + (row0 + r) * D + cg * 16;
#pragma unroll
    for (int jj = 0; jj < 4; ++jj) {
      *reinterpret_cast<float4*>(orow + (((jj + rg) & 3) << 2)) = acc[r][jj];
    }
  }
}

extern "C" void kernel_launch(void* const* d_in, const int* in_sizes, int n_in,
                              void* d_out, int out_size, void* d_ws,
                              size_t ws_size, hipStream_t stream) {
  const float* x = (const float*)d_in[0];
  const int* ei = (const int*)d_in[1];  // [2, E]: first E = src, next E = dst
  const float* W = (const float*)d_in[2];
  float* out = (float*)d_out;

  const int N = in_sizes[0] / D;
  const int E = in_sizes[1] / 2;

  // Workspace layout (ints): counts[N] | offs[N+1] | cursor[N] | esrc[E]
  int* counts = (int*)d_ws;
  int* offs = counts + N;
  int* cursor = offs + N + 1;
  int* esrc = cursor + N;

  hipMemsetAsync(counts, 0, (size_t)N * sizeof(int), stream);

  const int nb_e = (E + 255) / 256;
  gnn_hist<<<nb_e, 256, 0, stream>>>(ei, counts, E);
  gnn_scan<<<1, 1024, 0, stream>>>(counts, offs, cursor, N);
  gnn_fill<<<nb_e, 256, 0, stream>>>(ei, cursor, esrc, E);
  gnn_gather<<<(N + 7) / 8, 256, 0, stream>>>(x, offs, esrc, out, N);
  gnn_gemm<<<(N + 127) / 128, 256, 0, stream>>>(W, out, N);
}

// Round 3
// 214.982 us; speedup vs baseline: 6.5187x; 1.4523x over previous
//
#include <hip/hip_runtime.h>

static constexpr int D = 128;

// ---------------------------------------------------------------------------
// CSR build, phase A: histogram of dst. counts must be pre-zeroed.
// ---------------------------------------------------------------------------
__global__ __launch_bounds__(256) void gnn_hist(const int* __restrict__ ei,
                                                int* __restrict__ counts,
                                                int E) {
  int e = blockIdx.x * 256 + threadIdx.x;
  if (e < E) atomicAdd(&counts[ei[E + e]], 1);
}

// ---------------------------------------------------------------------------
// Hierarchical scan, level 1: each block scans a 1024-element tile of counts.
// Writes local exclusive prefixes into offs[0..N) and block total to bsum[b].
// ---------------------------------------------------------------------------
__global__ __launch_bounds__(256) void gnn_scan_a(
    const int* __restrict__ counts, int* __restrict__ offs,
    int* __restrict__ bsum, int N) {
  __shared__ int sc[256];
  const int tid = threadIdx.x;
  const int idx = blockIdx.x * 1024 + tid * 4;

  int4 v = make_int4(0, 0, 0, 0);
  if (idx + 3 < N) {
    v = *reinterpret_cast<const int4*>(counts + idx);
  } else {
    if (idx + 0 < N) v.x = counts[idx + 0];
    if (idx + 1 < N) v.y = counts[idx + 1];
    if (idx + 2 < N) v.z = counts[idx + 2];
    if (idx + 3 < N) v.w = counts[idx + 3];
  }
  sc[tid] = v.x + v.y + v.z + v.w;
  __syncthreads();
  for (int off = 1; off < 256; off <<= 1) {
    int t = (tid >= off) ? sc[tid - off] : 0;
    __syncthreads();
    sc[tid] += t;
    __syncthreads();
  }
  int ex = (tid > 0) ? sc[tid - 1] : 0;
  int4 p = make_int4(ex, ex + v.x, ex + v.x + v.y, ex + v.x + v.y + v.z);
  if (idx + 3 < N) {
    *reinterpret_cast<int4*>(offs + idx) = p;
  } else {
    if (idx + 0 < N) offs[idx + 0] = p.x;
    if (idx + 1 < N) offs[idx + 1] = p.y;
    if (idx + 2 < N) offs[idx + 2] = p.z;
    if (idx + 3 < N) offs[idx + 3] = p.w;
  }
  if (tid == 255) bsum[blockIdx.x] = sc[255];
}

// ---------------------------------------------------------------------------
// Hierarchical scan, level 2: one block scans bsum[0..nb) -> exclusive, and
// writes the grand total to offs[N]. Requires nb <= 256.
// ---------------------------------------------------------------------------
__global__ __launch_bounds__(256) void gnn_scan_b(int* __restrict__ bsum,
                                                  int* __restrict__ offs_N,
                                                  int nb) {
  __shared__ int sc[256];
  const int tid = threadIdx.x;
  int v = (tid < nb) ? bsum[tid] : 0;
  sc[tid] = v;
  __syncthreads();
  for (int off = 1; off < 256; off <<= 1) {
    int t = (tid >= off) ? sc[tid - off] : 0;
    __syncthreads();
    sc[tid] += t;
    __syncthreads();
  }
  if (tid < nb) bsum[tid] = sc[tid] - v;  // exclusive
  if (tid == nb - 1) *offs_N = sc[tid];   // grand total (== E)
}

// ---------------------------------------------------------------------------
// Hierarchical scan, level 3: offs[i] += bsum_ex[tile]; cursor[i] = offs[i].
// ---------------------------------------------------------------------------
__global__ __launch_bounds__(256) void gnn_scan_c(int* __restrict__ offs,
                                                  int* __restrict__ cursor,
                                                  const int* __restrict__ bsum,
                                                  int N) {
  const int idx = blockIdx.x * 1024 + threadIdx.x * 4;
  const int add = bsum[blockIdx.x];
  if (idx + 3 < N) {
    int4 v = *reinterpret_cast<int4*>(offs + idx);
    v.x += add;
    v.y += add;
    v.z += add;
    v.w += add;
    *reinterpret_cast<int4*>(offs + idx) = v;
    *reinterpret_cast<int4*>(cursor + idx) = v;
  } else {
#pragma unroll
    for (int i = 0; i < 4; ++i) {
      if (idx + i < N) {
        int t = offs[idx + i] + add;
        offs[idx + i] = t;
        cursor[idx + i] = t;
      }
    }
  }
}

// ---------------------------------------------------------------------------
// CSR build, phase C: scatter each edge's src into its dst segment.
// ---------------------------------------------------------------------------
__global__ __launch_bounds__(256) void gnn_fill(const int* __restrict__ ei,
                                                int* __restrict__ cursor,
                                                int* __restrict__ esrc,
                                                int E) {
  int e = blockIdx.x * 256 + threadIdx.x;
  if (e >= E) return;
  int s = ei[e];
  int d = ei[E + e];
  int slot = atomicAdd(&cursor[d], 1);
  esrc[slot] = s;
}

// ---------------------------------------------------------------------------
// Gather: aggs[j] = x[j] + sum_{e in seg(j)} x[esrc[e]].
// 32 lanes per node, one float4 per lane; x fully L3-resident.
// ---------------------------------------------------------------------------
__global__ __launch_bounds__(256) void gnn_gather(const float* __restrict__ x,
                                                  const int* __restrict__ offs,
                                                  const int* __restrict__ esrc,
                                                  float* __restrict__ aggs,
                                                  int N) {
  int j = blockIdx.x * 8 + (threadIdx.x >> 5);
  if (j >= N) return;
  int c = threadIdx.x & 31;
  const float4* x4 = reinterpret_cast<const float4*>(x);
  float4 acc = x4[j * 32 + c];  // self loop
  const int b = offs[j], en = offs[j + 1];
  for (int e = b; e < en; ++e) {
    int s = esrc[e];
    float4 v = x4[s * 32 + c];
    acc.x += v.x;
    acc.y += v.y;
    acc.z += v.z;
    acc.w += v.w;
  }
  reinterpret_cast<float4*>(aggs)[j * 32 + c] = acc;
}

// ---------------------------------------------------------------------------
// GEMM, IN PLACE on hx (= d_out): hx[i][o] <- sum_k hx[i][k] * W[o][k].
// Each block owns rows [blockIdx*128, +128); reads them, barriers, stores.
// ---------------------------------------------------------------------------
__global__ __launch_bounds__(256) void gnn_gemm(const float* __restrict__ W,
                                                float* hx, int N) {
  __shared__ float Wt[D * D];  // 64 KB: Wt[k*128 + o]
  const int tid = threadIdx.x;

  for (int idx = tid; idx < D * D; idx += 256) {
    int o = idx >> 7, k = idx & 127;
    Wt[k * D + o] = W[idx];
  }
  __syncthreads();

  const int cg = tid & 7;   // columns cg*16 .. cg*16+15
  const int rg = tid >> 3;  // rows row0 .. row0+3
  const long row0 = (long)blockIdx.x * 128 + (long)rg * 4;

  float4 acc[4][4];
#pragma unroll
  for (int r = 0; r < 4; ++r)
#pragma unroll
    for (int j = 0; j < 4; ++j) acc[r][j] = make_float4(0.f, 0.f, 0.f, 0.f);

  long rofs[4];
  bool val[4];
#pragma unroll
  for (int r = 0; r < 4; ++r) {
    long rr = row0 + r;
    val[r] = rr < N;
    rofs[r] = (val[r] ? rr : (long)(N - 1)) * (D / 4);
  }

  const float4* hx4 = reinterpret_cast<const float4*>(hx);

  for (int k4 = 0; k4 < D / 4; ++k4) {
    float a[4][4];
#pragma unroll
    for (int r = 0; r < 4; ++r) {
      float4 av = hx4[rofs[r] + k4];
      a[r][0] = av.x;
      a[r][1] = av.y;
      a[r][2] = av.z;
      a[r][3] = av.w;
    }
#pragma unroll
    for (int kk = 0; kk < 4; ++kk) {
      const int k = k4 * 4 + kk;
      const float* wrow = &Wt[k * D + cg * 16];
#pragma unroll
      for (int jj = 0; jj < 4; ++jj) {
        const float4 wv =
            *reinterpret_cast<const float4*>(wrow + (((jj + rg) & 3) << 2));
#pragma unroll
        for (int r = 0; r < 4; ++r) {
          acc[r][jj].x += a[r][kk] * wv.x;
          acc[r][jj].y += a[r][kk] * wv.y;
          acc[r][jj].z += a[r][kk] * wv.z;
          acc[r][jj].w += a[r][kk] * wv.w;
        }
      }
    }
  }

  __syncthreads();  // all reads of this block's rows complete before stores

#pragma unroll
  for (int r = 0; r < 4; ++r) {
    if (!val[r]) continue;
    float* orow = hx + (row0 + r) * D + cg * 16;
#pragma unroll
    for (int jj = 0; jj < 4; ++jj) {
      *reinterpret_cast<float4*>(orow + (((jj + rg) & 3) << 2)) = acc[r][jj];
    }
  }
}

extern "C" void kernel_launch(void* const* d_in, const int* in_sizes, int n_in,
                              void* d_out, int out_size, void* d_ws,
                              size_t ws_size, hipStream_t stream) {
  const float* x = (const float*)d_in[0];
  const int* ei = (const int*)d_in[1];  // [2, E]: first E = src, next E = dst
  const float* W = (const float*)d_in[2];
  float* out = (float*)d_out;

  const int N = in_sizes[0] / D;
  const int E = in_sizes[1] / 2;

  // Workspace (ints): counts[N] | offs[N+1] | cursor[N] | bsum[256] | esrc[E]
  int* counts = (int*)d_ws;
  int* offs = counts + N;
  int* cursor = offs + N + 1;
  int* bsum = cursor + N;
  int* esrc = bsum + 256;

  hipMemsetAsync(counts, 0, (size_t)N * sizeof(int), stream);

  const int nb_e = (E + 255) / 256;
  const int nb_scan = (N + 1023) / 1024;  // 49 for N=50000 (<=256 required)

  gnn_hist<<<nb_e, 256, 0, stream>>>(ei, counts, E);
  gnn_scan_a<<<nb_scan, 256, 0, stream>>>(counts, offs, bsum, N);
  gnn_scan_b<<<1, 256, 0, stream>>>(bsum, offs + N, nb_scan);
  gnn_scan_c<<<nb_scan, 256, 0, stream>>>(offs, cursor, bsum, N);
  gnn_fill<<<nb_e, 256, 0, stream>>>(ei, cursor, esrc, E);
  gnn_gather<<<(N + 7) / 8, 256, 0, stream>>>(x, offs, esrc, out, N);
  gnn_gemm<<<(N + 127) / 128, 256, 0, stream>>>(W, out, N);
}

// Round 4
// 196.162 us; speedup vs baseline: 7.1441x; 1.0959x over previous
//
#include <hip/hip_runtime.h>

static constexpr int D = 128;

// ---------------------------------------------------------------------------
// Convert x (fp32) -> xh (bf16, RNE). 8 elems/thread: 2x float4 in, uint4 out.
// ---------------------------------------------------------------------------
__device__ inline unsigned bf16pk(float a, float b) {
  unsigned ua = __float_as_uint(a), ub = __float_as_uint(b);
  ua = (ua + 0x7fffu + ((ua >> 16) & 1u)) >> 16;         // elem0 -> low 16
  ub = (ub + 0x7fffu + ((ub >> 16) & 1u)) & 0xffff0000u; // elem1 -> high 16
  return ua | ub;
}

__global__ __launch_bounds__(256) void gnn_cvt(const float* __restrict__ x,
                                               unsigned* __restrict__ xh,
                                               int total16) {  // total16 = N*16
  int i = blockIdx.x * 256 + threadIdx.x;
  if (i >= total16) return;
  const float4* x4 = reinterpret_cast<const float4*>(x);
  float4 a = x4[2 * i], b = x4[2 * i + 1];
  uint4 o;
  o.x = bf16pk(a.x, a.y);
  o.y = bf16pk(a.z, a.w);
  o.z = bf16pk(b.x, b.y);
  o.w = bf16pk(b.z, b.w);
  reinterpret_cast<uint4*>(xh)[i] = o;
}

// ---------------------------------------------------------------------------
// CSR build, phase A: histogram of dst. counts must be pre-zeroed.
// ---------------------------------------------------------------------------
__global__ __launch_bounds__(256) void gnn_hist(const int* __restrict__ ei,
                                                int* __restrict__ counts,
                                                int E) {
  int e = blockIdx.x * 256 + threadIdx.x;
  if (e < E) atomicAdd(&counts[ei[E + e]], 1);
}

// ---------------------------------------------------------------------------
// Hierarchical scan, level 1: 1024-elem tiles -> local prefixes + block sums.
// ---------------------------------------------------------------------------
__global__ __launch_bounds__(256) void gnn_scan_a(
    const int* __restrict__ counts, int* __restrict__ offs,
    int* __restrict__ bsum, int N) {
  __shared__ int sc[256];
  const int tid = threadIdx.x;
  const int idx = blockIdx.x * 1024 + tid * 4;

  int4 v = make_int4(0, 0, 0, 0);
  if (idx + 3 < N) {
    v = *reinterpret_cast<const int4*>(counts + idx);
  } else {
    if (idx + 0 < N) v.x = counts[idx + 0];
    if (idx + 1 < N) v.y = counts[idx + 1];
    if (idx + 2 < N) v.z = counts[idx + 2];
    if (idx + 3 < N) v.w = counts[idx + 3];
  }
  sc[tid] = v.x + v.y + v.z + v.w;
  __syncthreads();
  for (int off = 1; off < 256; off <<= 1) {
    int t = (tid >= off) ? sc[tid - off] : 0;
    __syncthreads();
    sc[tid] += t;
    __syncthreads();
  }
  int ex = (tid > 0) ? sc[tid - 1] : 0;
  int4 p = make_int4(ex, ex + v.x, ex + v.x + v.y, ex + v.x + v.y + v.z);
  if (idx + 3 < N) {
    *reinterpret_cast<int4*>(offs + idx) = p;
  } else {
    if (idx + 0 < N) offs[idx + 0] = p.x;
    if (idx + 1 < N) offs[idx + 1] = p.y;
    if (idx + 2 < N) offs[idx + 2] = p.z;
    if (idx + 3 < N) offs[idx + 3] = p.w;
  }
  if (tid == 255) bsum[blockIdx.x] = sc[255];
}

// ---------------------------------------------------------------------------
// Hierarchical scan, level 2: exclusive-scan block sums; grand total->offs[N].
// ---------------------------------------------------------------------------
__global__ __launch_bounds__(256) void gnn_scan_b(int* __restrict__ bsum,
                                                  int* __restrict__ offs_N,
                                                  int nb) {
  __shared__ int sc[256];
  const int tid = threadIdx.x;
  int v = (tid < nb) ? bsum[tid] : 0;
  sc[tid] = v;
  __syncthreads();
  for (int off = 1; off < 256; off <<= 1) {
    int t = (tid >= off) ? sc[tid - off] : 0;
    __syncthreads();
    sc[tid] += t;
    __syncthreads();
  }
  if (tid < nb) bsum[tid] = sc[tid] - v;  // exclusive
  if (tid == nb - 1) *offs_N = sc[tid];   // grand total (== E)
}

// ---------------------------------------------------------------------------
// Hierarchical scan, level 3: add block prefix; duplicate into cursor.
// ---------------------------------------------------------------------------
__global__ __launch_bounds__(256) void gnn_scan_c(int* __restrict__ offs,
                                                  int* __restrict__ cursor,
                                                  const int* __restrict__ bsum,
                                                  int N) {
  const int idx = blockIdx.x * 1024 + threadIdx.x * 4;
  const int add = bsum[blockIdx.x];
  if (idx + 3 < N) {
    int4 v = *reinterpret_cast<int4*>(offs + idx);
    v.x += add;
    v.y += add;
    v.z += add;
    v.w += add;
    *reinterpret_cast<int4*>(offs + idx) = v;
    *reinterpret_cast<int4*>(cursor + idx) = v;
  } else {
#pragma unroll
    for (int i = 0; i < 4; ++i) {
      if (idx + i < N) {
        int t = offs[idx + i] + add;
        offs[idx + i] = t;
        cursor[idx + i] = t;
      }
    }
  }
}

// ---------------------------------------------------------------------------
// CSR build, phase C: scatter each edge's src into its dst segment.
// ---------------------------------------------------------------------------
__global__ __launch_bounds__(256) void gnn_fill(const int* __restrict__ ei,
                                                int* __restrict__ cursor,
                                                int* __restrict__ esrc,
                                                int E) {
  int e = blockIdx.x * 256 + threadIdx.x;
  if (e >= E) return;
  int s = ei[e];
  int d = ei[E + e];
  int slot = atomicAdd(&cursor[d], 1);
  esrc[slot] = s;
}

// ---------------------------------------------------------------------------
// Gather (bf16 source): aggs[j] = xh[j] + sum_{e in seg(j)} xh[esrc[e]],
// accumulated in fp32. 16 lanes per node; each lane one uint4 (8 bf16).
// Per-edge read volume: 256 B (vs 512 B fp32).
// ---------------------------------------------------------------------------
__global__ __launch_bounds__(256) void gnn_gather(
    const unsigned* __restrict__ xh, const int* __restrict__ offs,
    const int* __restrict__ esrc, float* __restrict__ aggs, int N) {
  int j = blockIdx.x * 16 + (threadIdx.x >> 4);
  if (j >= N) return;
  const int c = threadIdx.x & 15;  // lane's 8 columns: c*8 .. c*8+7
  const uint4* xh4 = reinterpret_cast<const uint4*>(xh);  // 16 uint4 per row

  float acc[8];
  {
    uint4 u = xh4[j * 16 + c];  // self loop
    acc[0] = __uint_as_float(u.x << 16);
    acc[1] = __uint_as_float(u.x & 0xffff0000u);
    acc[2] = __uint_as_float(u.y << 16);
    acc[3] = __uint_as_float(u.y & 0xffff0000u);
    acc[4] = __uint_as_float(u.z << 16);
    acc[5] = __uint_as_float(u.z & 0xffff0000u);
    acc[6] = __uint_as_float(u.w << 16);
    acc[7] = __uint_as_float(u.w & 0xffff0000u);
  }
  const int b = offs[j], en = offs[j + 1];
  for (int e = b; e < en; ++e) {
    int s = esrc[e];  // all 16 lanes same addr -> broadcast
    uint4 u = xh4[s * 16 + c];
    acc[0] += __uint_as_float(u.x << 16);
    acc[1] += __uint_as_float(u.x & 0xffff0000u);
    acc[2] += __uint_as_float(u.y << 16);
    acc[3] += __uint_as_float(u.y & 0xffff0000u);
    acc[4] += __uint_as_float(u.z << 16);
    acc[5] += __uint_as_float(u.z & 0xffff0000u);
    acc[6] += __uint_as_float(u.w << 16);
    acc[7] += __uint_as_float(u.w & 0xffff0000u);
  }
  float4* o = reinterpret_cast<float4*>(aggs) + j * 32 + c * 2;
  o[0] = make_float4(acc[0], acc[1], acc[2], acc[3]);
  o[1] = make_float4(acc[4], acc[5], acc[6], acc[7]);
}

// ---------------------------------------------------------------------------
// GEMM, IN PLACE on hx (= d_out): hx[i][o] <- sum_k hx[i][k] * W[o][k].
// Each block owns rows [blockIdx*128, +128); reads them, barriers, stores.
// ---------------------------------------------------------------------------
__global__ __launch_bounds__(256) void gnn_gemm(const float* __restrict__ W,
                                                float* hx, int N) {
  __shared__ float Wt[D * D];  // 64 KB: Wt[k*128 + o]
  const int tid = threadIdx.x;

  for (int idx = tid; idx < D * D; idx += 256) {
    int o = idx >> 7, k = idx & 127;
    Wt[k * D + o] = W[idx];
  }
  __syncthreads();

  const int cg = tid & 7;   // columns cg*16 .. cg*16+15
  const int rg = tid >> 3;  // rows row0 .. row0+3
  const long row0 = (long)blockIdx.x * 128 + (long)rg * 4;

  float4 acc[4][4];
#pragma unroll
  for (int r = 0; r < 4; ++r)
#pragma unroll
    for (int j = 0; j < 4; ++j) acc[r][j] = make_float4(0.f, 0.f, 0.f, 0.f);

  long rofs[4];
  bool val[4];
#pragma unroll
  for (int r = 0; r < 4; ++r) {
    long rr = row0 + r;
    val[r] = rr < N;
    rofs[r] = (val[r] ? rr : (long)(N - 1)) * (D / 4);
  }

  const float4* hx4 = reinterpret_cast<const float4*>(hx);

  for (int k4 = 0; k4 < D / 4; ++k4) {
    float a[4][4];
#pragma unroll
    for (int r = 0; r < 4; ++r) {
      float4 av = hx4[rofs[r] + k4];
      a[r][0] = av.x;
      a[r][1] = av.y;
      a[r][2] = av.z;
      a[r][3] = av.w;
    }
#pragma unroll
    for (int kk = 0; kk < 4; ++kk) {
      const int k = k4 * 4 + kk;
      const float* wrow = &Wt[k * D + cg * 16];
#pragma unroll
      for (int jj = 0; jj < 4; ++jj) {
        const float4 wv =
            *reinterpret_cast<const float4*>(wrow + (((jj + rg) & 3) << 2));
#pragma unroll
        for (int r = 0; r < 4; ++r) {
          acc[r][jj].x += a[r][kk] * wv.x;
          acc[r][jj].y += a[r][kk] * wv.y;
          acc[r][jj].z += a[r][kk] * wv.z;
          acc[r][jj].w += a[r][kk] * wv.w;
        }
      }
    }
  }

  __syncthreads();  // all reads of this block's rows complete before stores

#pragma unroll
  for (int r = 0; r < 4; ++r) {
    if (!val[r]) continue;
    float* orow = hx + (row0 + r) * D + cg * 16;
#pragma unroll
    for (int jj = 0; jj < 4; ++jj) {
      *reinterpret_cast<float4*>(orow + (((jj + rg) & 3) << 2)) = acc[r][jj];
    }
  }
}

extern "C" void kernel_launch(void* const* d_in, const int* in_sizes, int n_in,
                              void* d_out, int out_size, void* d_ws,
                              size_t ws_size, hipStream_t stream) {
  const float* x = (const float*)d_in[0];
  const int* ei = (const int*)d_in[1];  // [2, E]: first E = src, next E = dst
  const float* W = (const float*)d_in[2];
  float* out = (float*)d_out;

  const int N = in_sizes[0] / D;
  const int E = in_sizes[1] / 2;

  // Workspace: xh[N*D] bf16 (12.8 MB), then ints:
  //   counts[N] | offs[N+1] | cursor[N] | bsum[256] | esrc[E]   (~3.8 MB)
  unsigned* xh = (unsigned*)d_ws;                 // stored as N*16 uint4s
  int* counts = (int*)d_ws + (size_t)N * D / 2;   // N*D bf16 = N*D/2 uints
  int* offs = counts + N;
  int* cursor = offs + N + 1;
  int* bsum = cursor + N;
  int* esrc = bsum + 256;

  hipMemsetAsync(counts, 0, (size_t)N * sizeof(int), stream);

  const int nb_e = (E + 255) / 256;
  const int nb_scan = (N + 1023) / 1024;  // 49 for N=50000 (<=256 required)

  gnn_cvt<<<(N * 16 + 255) / 256, 256, 0, stream>>>(x, xh, N * 16);
  gnn_hist<<<nb_e, 256, 0, stream>>>(ei, counts, E);
  gnn_scan_a<<<nb_scan, 256, 0, stream>>>(counts, offs, bsum, N);
  gnn_scan_b<<<1, 256, 0, stream>>>(bsum, offs + N, nb_scan);
  gnn_scan_c<<<nb_scan, 256, 0, stream>>>(offs, cursor, bsum, N);
  gnn_fill<<<nb_e, 256, 0, stream>>>(ei, cursor, esrc, E);
  gnn_gather<<<(N + 15) / 16, 256, 0, stream>>>(xh, offs, esrc, out, N);
  gnn_gemm<<<(N + 127) / 128, 256, 0, stream>>>(W, out, N);
}

// Round 5
// 143.334 us; speedup vs baseline: 9.7772x; 1.3686x over previous
//
#include <hip/hip_runtime.h>

static constexpr int D = 128;
static constexpr int BSH = 9;         // nodes per bucket = 512
static constexpr int BSZ = 1 << BSH;  // 512
static constexpr int MAXB = 128;      // max buckets (supports N <= 65536)

// ---------------------------------------------------------------------------
// Convert x (fp32) -> xh (bf16, RNE). 8 elems/thread: 2x float4 in, uint4 out.
// ---------------------------------------------------------------------------
__device__ inline unsigned bf16pk(float a, float b) {
  unsigned ua = __float_as_uint(a), ub = __float_as_uint(b);
  ua = (ua + 0x7fffu + ((ua >> 16) & 1u)) >> 16;          // elem0 -> low 16
  ub = (ub + 0x7fffu + ((ub >> 16) & 1u)) & 0xffff0000u;  // elem1 -> high 16
  return ua | ub;
}

__global__ __launch_bounds__(256) void gnn_cvt(const float* __restrict__ x,
                                               unsigned* __restrict__ xh,
                                               int total16) {  // = N*16
  int i = blockIdx.x * 256 + threadIdx.x;
  if (i >= total16) return;
  const float4* x4 = reinterpret_cast<const float4*>(x);
  float4 a = x4[2 * i], b = x4[2 * i + 1];
  uint4 o;
  o.x = bf16pk(a.x, a.y);
  o.y = bf16pk(a.z, a.w);
  o.z = bf16pk(b.x, b.y);
  o.w = bf16pk(b.z, b.w);
  reinterpret_cast<uint4*>(xh)[i] = o;
}

// ---------------------------------------------------------------------------
// Bucket histogram: bcount[b] = #edges with dst in bucket b. LDS-staged, so
// global atomics are only nbuck per block. bcount pre-zeroed by memset.
// ---------------------------------------------------------------------------
__global__ __launch_bounds__(256) void gnn_bhist(const int* __restrict__ ei,
                                                 int* __restrict__ bcount,
                                                 int E) {
  __shared__ int cnt[MAXB];
  const int tid = threadIdx.x;
  if (tid < MAXB) cnt[tid] = 0;
  __syncthreads();
  const int base = blockIdx.x * 4096;
#pragma unroll
  for (int i = 0; i < 16; ++i) {
    int e = base + i * 256 + tid;
    if (e < E) atomicAdd(&cnt[ei[E + e] >> BSH], 1);
  }
  __syncthreads();
  if (tid < MAXB && cnt[tid]) atomicAdd(&bcount[tid], cnt[tid]);
}

// ---------------------------------------------------------------------------
// Scan bucket counts (one block): bbase = exclusive prefix (+ total at [nbuck]),
// bcur = working cursors for the partition kernel. Re-inits bcur every call.
// ---------------------------------------------------------------------------
__global__ __launch_bounds__(MAXB) void gnn_bscan(const int* __restrict__ bcount,
                                                  int* __restrict__ bbase,
                                                  int* __restrict__ bcur,
                                                  int nbuck) {
  __shared__ int sc[MAXB];
  const int tid = threadIdx.x;
  int v = (tid < nbuck) ? bcount[tid] : 0;
  sc[tid] = v;
  __syncthreads();
  for (int off = 1; off < MAXB; off <<= 1) {
    int t = (tid >= off) ? sc[tid - off] : 0;
    __syncthreads();
    sc[tid] += t;
    __syncthreads();
  }
  int ex = sc[tid] - v;
  bbase[tid] = ex;
  bcur[tid] = ex;
  if (tid == nbuck - 1) bbase[nbuck] = sc[tid];  // total == E
}

// ---------------------------------------------------------------------------
// Partition edges into bucket-contiguous ebuf[(src,dst)]. Per-block LDS bucket
// counts -> one global atomic per (block,bucket) reserves a contiguous run ->
// direct writes. Runs are fully written by one block => full-line HBM writes.
// ---------------------------------------------------------------------------
__global__ __launch_bounds__(256) void gnn_bpart(const int* __restrict__ ei,
                                                 int* __restrict__ bcur,
                                                 uint2* __restrict__ ebuf,
                                                 int E) {
  __shared__ int cnt[MAXB];
  __shared__ int gbase[MAXB];
  const int tid = threadIdx.x;
  if (tid < MAXB) cnt[tid] = 0;
  __syncthreads();
  const int base = blockIdx.x * 4096;
  int sv[16], dv[16], rk[16];
#pragma unroll
  for (int i = 0; i < 16; ++i) {
    int e = base + i * 256 + tid;
    rk[i] = -1;
    if (e < E) {
      sv[i] = ei[e];
      dv[i] = ei[E + e];
      rk[i] = atomicAdd(&cnt[dv[i] >> BSH], 1);
    }
  }
  __syncthreads();
  if (tid < MAXB && cnt[tid]) gbase[tid] = atomicAdd(&bcur[tid], cnt[tid]);
  __syncthreads();
#pragma unroll
  for (int i = 0; i < 16; ++i) {
    if (rk[i] >= 0) {
      int b = dv[i] >> BSH;
      ebuf[gbase[b] + rk[i]] = make_uint2((unsigned)sv[i], (unsigned)dv[i]);
    }
  }
}

// ---------------------------------------------------------------------------
// Per-bucket CSR finalize: LDS node-histogram over the bucket's edges, LDS
// scan -> offs (global), LDS cursors -> esrc[slot]=src. All edge-granular
// atomics are LDS; esrc writes land in a hot ~32KB window.
// ---------------------------------------------------------------------------
__global__ __launch_bounds__(1024) void gnn_bfill(
    const uint2* __restrict__ ebuf, const int* __restrict__ bbase,
    int* __restrict__ offs, int* __restrict__ esrc, int N, int nbuck) {
  __shared__ int cnt[BSZ];
  const int tid = threadIdx.x;
  const int bnode = blockIdx.x << BSH;
  const int ebeg = bbase[blockIdx.x];
  const int eend = bbase[blockIdx.x + 1];
  const int ne = eend - ebeg;
  if (tid < BSZ) cnt[tid] = 0;
  __syncthreads();
  for (int k = tid; k < ne; k += 1024)
    atomicAdd(&cnt[ebuf[ebeg + k].y & (BSZ - 1)], 1);
  __syncthreads();
  int v = (tid < BSZ) ? cnt[tid] : 0;
  // inclusive Hillis-Steele over BSZ entries (all 1024 threads hit the syncs)
  for (int off = 1; off < BSZ; off <<= 1) {
    int t = (tid >= off && tid < BSZ) ? cnt[tid - off] : 0;
    __syncthreads();
    if (tid < BSZ) cnt[tid] += t;
    __syncthreads();
  }
  int gslot = 0;
  if (tid < BSZ) {
    gslot = ebeg + cnt[tid] - v;  // global exclusive base for this node
    if (bnode + tid < N) offs[bnode + tid] = gslot;
  }
  if (blockIdx.x == nbuck - 1 && tid == 0) offs[N] = eend;
  __syncthreads();  // scan reads fully done before cnt is repurposed
  if (tid < BSZ) cnt[tid] = gslot;  // cnt becomes the global-slot cursor
  __syncthreads();
  for (int k = tid; k < ne; k += 1024) {
    uint2 u = ebuf[ebeg + k];
    int slot = atomicAdd(&cnt[u.y & (BSZ - 1)], 1);
    esrc[slot] = (int)u.x;
  }
}

// ---------------------------------------------------------------------------
// Gather (bf16 source): aggs[j] = xh[j] + sum_{e in seg(j)} xh[esrc[e]],
// fp32 accumulate. 16 lanes per node; each lane one uint4 (8 bf16).
// ---------------------------------------------------------------------------
__global__ __launch_bounds__(256) void gnn_gather(
    const unsigned* __restrict__ xh, const int* __restrict__ offs,
    const int* __restrict__ esrc, float* __restrict__ aggs, int N) {
  int j = blockIdx.x * 16 + (threadIdx.x >> 4);
  if (j >= N) return;
  const int c = threadIdx.x & 15;
  const uint4* xh4 = reinterpret_cast<const uint4*>(xh);  // 16 uint4 per row

  float acc[8];
  {
    uint4 u = xh4[j * 16 + c];  // self loop
    acc[0] = __uint_as_float(u.x << 16);
    acc[1] = __uint_as_float(u.x & 0xffff0000u);
    acc[2] = __uint_as_float(u.y << 16);
    acc[3] = __uint_as_float(u.y & 0xffff0000u);
    acc[4] = __uint_as_float(u.z << 16);
    acc[5] = __uint_as_float(u.z & 0xffff0000u);
    acc[6] = __uint_as_float(u.w << 16);
    acc[7] = __uint_as_float(u.w & 0xffff0000u);
  }
  const int b = offs[j], en = offs[j + 1];
  for (int e = b; e < en; ++e) {
    int s = esrc[e];
    uint4 u = xh4[s * 16 + c];
    acc[0] += __uint_as_float(u.x << 16);
    acc[1] += __uint_as_float(u.x & 0xffff0000u);
    acc[2] += __uint_as_float(u.y << 16);
    acc[3] += __uint_as_float(u.y & 0xffff0000u);
    acc[4] += __uint_as_float(u.z << 16);
    acc[5] += __uint_as_float(u.z & 0xffff0000u);
    acc[6] += __uint_as_float(u.w << 16);
    acc[7] += __uint_as_float(u.w & 0xffff0000u);
  }
  float4* o = reinterpret_cast<float4*>(aggs) + j * 32 + c * 2;
  o[0] = make_float4(acc[0], acc[1], acc[2], acc[3]);
  o[1] = make_float4(acc[4], acc[5], acc[6], acc[7]);
}

// ---------------------------------------------------------------------------
// GEMM, IN PLACE on hx (= d_out): hx[i][o] <- sum_k hx[i][k] * W[o][k].
// Each block owns rows [blockIdx*128, +128); reads them, barriers, stores.
// ---------------------------------------------------------------------------
__global__ __launch_bounds__(256) void gnn_gemm(const float* __restrict__ W,
                                                float* hx, int N) {
  __shared__ float Wt[D * D];  // 64 KB: Wt[k*128 + o]
  const int tid = threadIdx.x;

  for (int idx = tid; idx < D * D; idx += 256) {
    int o = idx >> 7, k = idx & 127;
    Wt[k * D + o] = W[idx];
  }
  __syncthreads();

  const int cg = tid & 7;   // columns cg*16 .. cg*16+15
  const int rg = tid >> 3;  // rows row0 .. row0+3
  const long row0 = (long)blockIdx.x * 128 + (long)rg * 4;

  float4 acc[4][4];
#pragma unroll
  for (int r = 0; r < 4; ++r)
#pragma unroll
    for (int j = 0; j < 4; ++j) acc[r][j] = make_float4(0.f, 0.f, 0.f, 0.f);

  long rofs[4];
  bool val[4];
#pragma unroll
  for (int r = 0; r < 4; ++r) {
    long rr = row0 + r;
    val[r] = rr < N;
    rofs[r] = (val[r] ? rr : (long)(N - 1)) * (D / 4);
  }

  const float4* hx4 = reinterpret_cast<const float4*>(hx);

  for (int k4 = 0; k4 < D / 4; ++k4) {
    float a[4][4];
#pragma unroll
    for (int r = 0; r < 4; ++r) {
      float4 av = hx4[rofs[r] + k4];
      a[r][0] = av.x;
      a[r][1] = av.y;
      a[r][2] = av.z;
      a[r][3] = av.w;
    }
#pragma unroll
    for (int kk = 0; kk < 4; ++kk) {
      const int k = k4 * 4 + kk;
      const float* wrow = &Wt[k * D + cg * 16];
#pragma unroll
      for (int jj = 0; jj < 4; ++jj) {
        const float4 wv =
            *reinterpret_cast<const float4*>(wrow + (((jj + rg) & 3) << 2));
#pragma unroll
        for (int r = 0; r < 4; ++r) {
          acc[r][jj].x += a[r][kk] * wv.x;
          acc[r][jj].y += a[r][kk] * wv.y;
          acc[r][jj].z += a[r][kk] * wv.z;
          acc[r][jj].w += a[r][kk] * wv.w;
        }
      }
    }
  }

  __syncthreads();  // all reads of this block's rows complete before stores

#pragma unroll
  for (int r = 0; r < 4; ++r) {
    if (!val[r]) continue;
    float* orow = hx + (row0 + r) * D + cg * 16;
#pragma unroll
    for (int jj = 0; jj < 4; ++jj) {
      *reinterpret_cast<float4*>(orow + (((jj + rg) & 3) << 2)) = acc[r][jj];
    }
  }
}

extern "C" void kernel_launch(void* const* d_in, const int* in_sizes, int n_in,
                              void* d_out, int out_size, void* d_ws,
                              size_t ws_size, hipStream_t stream) {
  const float* x = (const float*)d_in[0];
  const int* ei = (const int*)d_in[1];  // [2, E]: first E = src, next E = dst
  const float* W = (const float*)d_in[2];
  float* out = (float*)d_out;

  const int N = in_sizes[0] / D;
  const int E = in_sizes[1] / 2;
  const int nbuck = (N + BSZ - 1) >> BSH;  // 98 for N=50000 (<= MAXB)

  // Workspace: xh bf16 (12.8MB) | ebuf uint2 (6.4MB) | esrc (3.2MB) |
  //            offs[N+1] | bcount[MAXB] | bbase[MAXB+1] | bcur[MAXB]
  unsigned* xh = (unsigned*)d_ws;                   // N*D/2 uints
  uint2* ebuf = (uint2*)(xh + (size_t)N * D / 2);   // E entries
  int* esrc = (int*)(ebuf + E);                     // E ints
  int* offs = esrc + E;                             // N+1
  int* bcount = offs + N + 1;
  int* bbase = bcount + MAXB;
  int* bcur = bbase + MAXB + 1;

  hipMemsetAsync(bcount, 0, MAXB * sizeof(int), stream);

  const int nbp = (E + 4095) / 4096;

  gnn_cvt<<<(N * 16 + 255) / 256, 256, 0, stream>>>(x, xh, N * 16);
  gnn_bhist<<<nbp, 256, 0, stream>>>(ei, bcount, E);
  gnn_bscan<<<1, MAXB, 0, stream>>>(bcount, bbase, bcur, nbuck);
  gnn_bpart<<<nbp, 256, 0, stream>>>(ei, bcur, ebuf, E);
  gnn_bfill<<<nbuck, 1024, 0, stream>>>(ebuf, bbase, offs, esrc, N, nbuck);
  gnn_gather<<<(N + 15) / 16, 256, 0, stream>>>(xh, offs, esrc, out, N);
  gnn_gemm<<<(N + 127) / 128, 256, 0, stream>>>(W, out, N);
}

// Round 6
// 109.345 us; speedup vs baseline: 12.8164x; 1.3108x over previous
//
#include <hip/hip_runtime.h>

static constexpr int D = 128;
static constexpr int BSH = 9;         // nodes per bucket = 512
static constexpr int BSZ = 1 << BSH;  // 512
static constexpr int MAXB = 128;      // max buckets (supports N <= 65536)

typedef __attribute__((ext_vector_type(8))) short bf16x8;
typedef __attribute__((ext_vector_type(4))) float f32x4;

// ---------------------------------------------------------------------------
// Pack two fp32 into two bf16 (RNE), elem0 -> low 16, elem1 -> high 16.
// ---------------------------------------------------------------------------
__device__ inline unsigned bf16pk(float a, float b) {
  unsigned ua = __float_as_uint(a), ub = __float_as_uint(b);
  ua = (ua + 0x7fffu + ((ua >> 16) & 1u)) >> 16;
  ub = (ub + 0x7fffu + ((ub >> 16) & 1u)) & 0xffff0000u;
  return ua | ub;
}

// ---------------------------------------------------------------------------
// Convert x (fp32) -> xh (bf16). 8 elems/thread.
// ---------------------------------------------------------------------------
__global__ __launch_bounds__(256) void gnn_cvt(const float* __restrict__ x,
                                               unsigned* __restrict__ xh,
                                               int total16) {  // = N*16
  int i = blockIdx.x * 256 + threadIdx.x;
  if (i >= total16) return;
  const float4* x4 = reinterpret_cast<const float4*>(x);
  float4 a = x4[2 * i], b = x4[2 * i + 1];
  uint4 o;
  o.x = bf16pk(a.x, a.y);
  o.y = bf16pk(a.z, a.w);
  o.z = bf16pk(b.x, b.y);
  o.w = bf16pk(b.z, b.w);
  reinterpret_cast<uint4*>(xh)[i] = o;
}

// ---------------------------------------------------------------------------
// Bucket histogram (LDS-staged; bcount pre-zeroed).
// ---------------------------------------------------------------------------
__global__ __launch_bounds__(256) void gnn_bhist(const int* __restrict__ ei,
                                                 int* __restrict__ bcount,
                                                 int E) {
  __shared__ int cnt[MAXB];
  const int tid = threadIdx.x;
  if (tid < MAXB) cnt[tid] = 0;
  __syncthreads();
  const int base = blockIdx.x * 4096;
#pragma unroll
  for (int i = 0; i < 16; ++i) {
    int e = base + i * 256 + tid;
    if (e < E) atomicAdd(&cnt[ei[E + e] >> BSH], 1);
  }
  __syncthreads();
  if (tid < MAXB && cnt[tid]) atomicAdd(&bcount[tid], cnt[tid]);
}

// ---------------------------------------------------------------------------
// Scan bucket counts (one block) -> bbase (+total), bcur.
// ---------------------------------------------------------------------------
__global__ __launch_bounds__(MAXB) void gnn_bscan(const int* __restrict__ bcount,
                                                  int* __restrict__ bbase,
                                                  int* __restrict__ bcur,
                                                  int nbuck) {
  __shared__ int sc[MAXB];
  const int tid = threadIdx.x;
  int v = (tid < nbuck) ? bcount[tid] : 0;
  sc[tid] = v;
  __syncthreads();
  for (int off = 1; off < MAXB; off <<= 1) {
    int t = (tid >= off) ? sc[tid - off] : 0;
    __syncthreads();
    sc[tid] += t;
    __syncthreads();
  }
  int ex = sc[tid] - v;
  bbase[tid] = ex;
  bcur[tid] = ex;
  if (tid == nbuck - 1) bbase[nbuck] = sc[tid];  // total == E
}

// ---------------------------------------------------------------------------
// Partition edges into bucket-contiguous ebuf[(src,dst)].
// ---------------------------------------------------------------------------
__global__ __launch_bounds__(256) void gnn_bpart(const int* __restrict__ ei,
                                                 int* __restrict__ bcur,
                                                 uint2* __restrict__ ebuf,
                                                 int E) {
  __shared__ int cnt[MAXB];
  __shared__ int gbase[MAXB];
  const int tid = threadIdx.x;
  if (tid < MAXB) cnt[tid] = 0;
  __syncthreads();
  const int base = blockIdx.x * 4096;
  int sv[16], dv[16], rk[16];
#pragma unroll
  for (int i = 0; i < 16; ++i) {
    int e = base + i * 256 + tid;
    rk[i] = -1;
    if (e < E) {
      sv[i] = ei[e];
      dv[i] = ei[E + e];
      rk[i] = atomicAdd(&cnt[dv[i] >> BSH], 1);
    }
  }
  __syncthreads();
  if (tid < MAXB && cnt[tid]) gbase[tid] = atomicAdd(&bcur[tid], cnt[tid]);
  __syncthreads();
#pragma unroll
  for (int i = 0; i < 16; ++i) {
    if (rk[i] >= 0) {
      int b = dv[i] >> BSH;
      ebuf[gbase[b] + rk[i]] = make_uint2((unsigned)sv[i], (unsigned)dv[i]);
    }
  }
}

// ---------------------------------------------------------------------------
// Per-bucket CSR finalize (all edge-granular atomics in LDS).
// ---------------------------------------------------------------------------
__global__ __launch_bounds__(1024) void gnn_bfill(
    const uint2* __restrict__ ebuf, const int* __restrict__ bbase,
    int* __restrict__ offs, int* __restrict__ esrc, int N, int nbuck) {
  __shared__ int cnt[BSZ];
  const int tid = threadIdx.x;
  const int bnode = blockIdx.x << BSH;
  const int ebeg = bbase[blockIdx.x];
  const int eend = bbase[blockIdx.x + 1];
  const int ne = eend - ebeg;
  if (tid < BSZ) cnt[tid] = 0;
  __syncthreads();
  for (int k = tid; k < ne; k += 1024)
    atomicAdd(&cnt[ebuf[ebeg + k].y & (BSZ - 1)], 1);
  __syncthreads();
  int v = (tid < BSZ) ? cnt[tid] : 0;
  for (int off = 1; off < BSZ; off <<= 1) {
    int t = (tid >= off && tid < BSZ) ? cnt[tid - off] : 0;
    __syncthreads();
    if (tid < BSZ) cnt[tid] += t;
    __syncthreads();
  }
  int gslot = 0;
  if (tid < BSZ) {
    gslot = ebeg + cnt[tid] - v;
    if (bnode + tid < N) offs[bnode + tid] = gslot;
  }
  if (blockIdx.x == nbuck - 1 && tid == 0) offs[N] = eend;
  __syncthreads();
  if (tid < BSZ) cnt[tid] = gslot;
  __syncthreads();
  for (int k = tid; k < ne; k += 1024) {
    uint2 u = ebuf[ebeg + k];
    int slot = atomicAdd(&cnt[u.y & (BSZ - 1)], 1);
    esrc[slot] = (int)u.x;
  }
}

// ---------------------------------------------------------------------------
// Gather (bf16 source, fp32 accumulate): aggs[j] = xh[j] + sum xh[esrc[e]].
// ---------------------------------------------------------------------------
__global__ __launch_bounds__(256) void gnn_gather(
    const unsigned* __restrict__ xh, const int* __restrict__ offs,
    const int* __restrict__ esrc, float* __restrict__ aggs, int N) {
  int j = blockIdx.x * 16 + (threadIdx.x >> 4);
  if (j >= N) return;
  const int c = threadIdx.x & 15;
  const uint4* xh4 = reinterpret_cast<const uint4*>(xh);

  float acc[8];
  {
    uint4 u = xh4[j * 16 + c];
    acc[0] = __uint_as_float(u.x << 16);
    acc[1] = __uint_as_float(u.x & 0xffff0000u);
    acc[2] = __uint_as_float(u.y << 16);
    acc[3] = __uint_as_float(u.y & 0xffff0000u);
    acc[4] = __uint_as_float(u.z << 16);
    acc[5] = __uint_as_float(u.z & 0xffff0000u);
    acc[6] = __uint_as_float(u.w << 16);
    acc[7] = __uint_as_float(u.w & 0xffff0000u);
  }
  const int b = offs[j], en = offs[j + 1];
  for (int e = b; e < en; ++e) {
    int s = esrc[e];
    uint4 u = xh4[s * 16 + c];
    acc[0] += __uint_as_float(u.x << 16);
    acc[1] += __uint_as_float(u.x & 0xffff0000u);
    acc[2] += __uint_as_float(u.y << 16);
    acc[3] += __uint_as_float(u.y & 0xffff0000u);
    acc[4] += __uint_as_float(u.z << 16);
    acc[5] += __uint_as_float(u.z & 0xffff0000u);
    acc[6] += __uint_as_float(u.w << 16);
    acc[7] += __uint_as_float(u.w & 0xffff0000u);
  }
  float4* o = reinterpret_cast<float4*>(aggs) + j * 32 + c * 2;
  o[0] = make_float4(acc[0], acc[1], acc[2], acc[3]);
  o[1] = make_float4(acc[4], acc[5], acc[6], acc[7]);
}

// ---------------------------------------------------------------------------
// MFMA GEMM, IN PLACE on hx (= d_out): hx[i][o] <- sum_k bf16(hx[i][k])*Wh[o][k]
// Block = 128 rows, 4 waves; wave owns 32 rows (2 m-tiles x 8 o-tiles of
// mfma_f32_16x16x32_bf16). W converted fp32->bf16 into padded LDS [128][136]
// (16B pad => 2-way-max bank aliasing, free). A-frags packed in-register from
// the fp32 agg. A and B use the SAME (l>>4,j)->k mapping, so the contraction
// is correct under any HW k-permutation; C/D store uses the verified
// col=lane&15, row=(lane>>4)*4+reg mapping. Each wave reads & writes the same
// disjoint 32-row range => in-place safe without barriers.
// ---------------------------------------------------------------------------
__global__ __launch_bounds__(256) void gnn_gemm_mfma(const float* __restrict__ W,
                                                     float* hx, int N) {
  __shared__ short Wh[D][136];  // row stride 272B = 17*16B
  const int tid = threadIdx.x;

  {  // W fp32 [o][k] -> LDS bf16 (padded rows)
    const float4* W4 = reinterpret_cast<const float4*>(W);
    for (int q = tid; q < D * D / 4; q += 256) {
      int o = q >> 5, kq = q & 31;  // 32 float4 per row
      float4 w = W4[q];
      uint2 p;
      p.x = bf16pk(w.x, w.y);
      p.y = bf16pk(w.z, w.w);
      *reinterpret_cast<uint2*>(&Wh[o][kq * 4]) = p;
    }
  }
  __syncthreads();

  const int wid = tid >> 6;  // wave 0..3
  const int l = tid & 63;
  const int lr = l & 15;  // A row-in-tile / B col / D col
  const int lg = l >> 4;  // k-group / D row-group
  const long rowbase = (long)blockIdx.x * 128 + wid * 32;

  // A fragments a[m][kb]: agg[row][kb*32 + lg*8 .. +7], packed to bf16.
  bf16x8 a[2][4];
  const float4* hx4 = reinterpret_cast<const float4*>(hx);
#pragma unroll
  for (int m = 0; m < 2; ++m) {
    long row = rowbase + m * 16 + lr;
    if (row >= N) row = N - 1;  // clamp stays inside this block's rows
#pragma unroll
    for (int kb = 0; kb < 4; ++kb) {
      float4 u = hx4[row * 32 + kb * 8 + lg * 2];
      float4 v = hx4[row * 32 + kb * 8 + lg * 2 + 1];
      union {
        uint4 u4;
        bf16x8 h;
      } c;
      c.u4.x = bf16pk(u.x, u.y);
      c.u4.y = bf16pk(u.z, u.w);
      c.u4.z = bf16pk(v.x, v.y);
      c.u4.w = bf16pk(v.z, v.w);
      a[m][kb] = c.h;
    }
  }

  f32x4 acc[2][8];
#pragma unroll
  for (int m = 0; m < 2; ++m)
#pragma unroll
    for (int ot = 0; ot < 8; ++ot) acc[m][ot] = (f32x4){0.f, 0.f, 0.f, 0.f};

#pragma unroll
  for (int ot = 0; ot < 8; ++ot) {
    bf16x8 b[4];
#pragma unroll
    for (int kb = 0; kb < 4; ++kb)
      b[kb] =
          *reinterpret_cast<const bf16x8*>(&Wh[ot * 16 + lr][kb * 32 + lg * 8]);
#pragma unroll
    for (int m = 0; m < 2; ++m)
#pragma unroll
      for (int kb = 0; kb < 4; ++kb)
        acc[m][ot] = __builtin_amdgcn_mfma_f32_16x16x32_bf16(a[m][kb], b[kb],
                                                             acc[m][ot], 0, 0, 0);
  }

  // Store: row = rowbase + m*16 + lg*4 + r, col = ot*16 + lr.
#pragma unroll
  for (int m = 0; m < 2; ++m) {
#pragma unroll
    for (int r = 0; r < 4; ++r) {
      long row = rowbase + m * 16 + lg * 4 + r;
      if (row >= N) continue;
#pragma unroll
      for (int ot = 0; ot < 8; ++ot)
        hx[row * D + ot * 16 + lr] = acc[m][ot][r];
    }
  }
}

extern "C" void kernel_launch(void* const* d_in, const int* in_sizes, int n_in,
                              void* d_out, int out_size, void* d_ws,
                              size_t ws_size, hipStream_t stream) {
  const float* x = (const float*)d_in[0];
  const int* ei = (const int*)d_in[1];  // [2, E]: first E = src, next E = dst
  const float* W = (const float*)d_in[2];
  float* out = (float*)d_out;

  const int N = in_sizes[0] / D;
  const int E = in_sizes[1] / 2;
  const int nbuck = (N + BSZ - 1) >> BSH;  // 98 for N=50000 (<= MAXB)

  // Workspace: xh bf16 (12.8MB) | ebuf uint2 (6.4MB) | esrc (3.2MB) |
  //            offs[N+1] | bcount[MAXB] | bbase[MAXB+1] | bcur[MAXB]
  unsigned* xh = (unsigned*)d_ws;                  // N*D/2 uints
  uint2* ebuf = (uint2*)(xh + (size_t)N * D / 2);  // E entries
  int* esrc = (int*)(ebuf + E);                    // E ints
  int* offs = esrc + E;                            // N+1
  int* bcount = offs + N + 1;
  int* bbase = bcount + MAXB;
  int* bcur = bbase + MAXB + 1;

  hipMemsetAsync(bcount, 0, MAXB * sizeof(int), stream);

  const int nbp = (E + 4095) / 4096;

  gnn_cvt<<<(N * 16 + 255) / 256, 256, 0, stream>>>(x, xh, N * 16);
  gnn_bhist<<<nbp, 256, 0, stream>>>(ei, bcount, E);
  gnn_bscan<<<1, MAXB, 0, stream>>>(bcount, bbase, bcur, nbuck);
  gnn_bpart<<<nbp, 256, 0, stream>>>(ei, bcur, ebuf, E);
  gnn_bfill<<<nbuck, 1024, 0, stream>>>(ebuf, bbase, offs, esrc, N, nbuck);
  gnn_gather<<<(N + 15) / 16, 256, 0, stream>>>(xh, offs, esrc, out, N);
  gnn_gemm_mfma<<<(N + 127) / 128, 256, 0, stream>>>(W, out, N);
}